// Round 10
// baseline (315.326 us; speedup 1.0000x reference)
//
#include <hip/hip_runtime.h>

// Sequential2D: out[i] = sum_{j in [max(0,i-2), i]} X[j] @ W[i,j]^T + sum_j b[i,j]
// X (8,32768,128) f32, W (8,8,128,128) f32, b (8,8,128) f32, out (8,32768,128) f32.
//
// R11: fused over i with X in REGISTERS. Each wg owns 64 batch rows, computes
// all 8 output blocks. X tiles are loaded once, straight into per-lane MFMA
// A-fragments (bf16), held in a 3-tile register window across the band --
// X never touches LDS. LDS holds only the W double-buffer (+bias) -> 69.6 KB,
// 2 wg/CU. Per step: issue W-next loads FIRST, X-next loads SECOND, so W's
// consumption (pack -> ds_write) waits vmcnt(#X-newer) and the X stream is
// NEVER drained; one raw s_barrier + lgkm-only wait per step. All 21 (i,j)
// steps statically unrolled (all register indices compile-time).

#define NOUT  8
#define NIN   8
#define DD    128
#define BATCH 32768
#define BAND  2
#define BM    64
#define XSTRIDE ((size_t)BATCH * DD)

typedef __attribute__((ext_vector_type(8))) short  short8;
typedef __attribute__((ext_vector_type(4))) float  floatx4;

__device__ __forceinline__ unsigned short f2bf(float f) {
    unsigned int u = __float_as_uint(f);
    u += 0x7fffu + ((u >> 16) & 1u);
    return (unsigned short)(u >> 16);
}

__device__ __forceinline__ short8 pack8(floatx4 f0, floatx4 f1) {
    short8 p;
    p[0] = (short)f2bf(f0[0]); p[1] = (short)f2bf(f0[1]);
    p[2] = (short)f2bf(f0[2]); p[3] = (short)f2bf(f0[3]);
    p[4] = (short)f2bf(f1[0]); p[5] = (short)f2bf(f1[1]);
    p[6] = (short)f2bf(f1[2]); p[7] = (short)f2bf(f1[3]);
    return p;
}

// One (i,j) step. All args are literals; dead branches fold away.
// A: pack X[I] raw->window (first step of phase I)
// B: issue W[NI,NJ] global loads (16 float4, stay in flight through D/E)
// C: issue X[I+1] raw loads (AFTER B => newer => W consume never drains them)
// D: 32 MFMAs vs LDS W buffer S&1
// E: epilogue for block-row I at the diagonal
// F: consume W (vmcnt leaves X in flight), ds_write buf (S+1)&1,
//    lgkm-only drain + raw barrier (X global loads survive).
#define STEP(S, I, J, FIRST, HASNEXT, NI, NJ, XISSUE)                           \
  {                                                                             \
    if (FIRST) {                                                                \
      _Pragma("unroll")                                                         \
      for (int ks = 0; ks < 4; ++ks)                                            \
        xf[(I) % 3][ks] = pack8(xr[2 * ks], xr[2 * ks + 1]);                    \
    }                                                                           \
    if (HASNEXT) {                                                              \
      const float* ws_ = W + (size_t)((NI) * NIN + (NJ)) * (DD * DD)            \
                           + (size_t)wrow * DD + whalf * 64;                    \
      _Pragma("unroll")                                                         \
      for (int w_ = 0; w_ < 16; ++w_)                                           \
        wreg[w_] = *(const floatx4*)(ws_ + w_ * 4);                             \
    }                                                                           \
    if (XISSUE) {                                                               \
      const float* xp_ = xb + (size_t)((I) + 1) * XSTRIDE;                      \
      _Pragma("unroll")                                                         \
      for (int c_ = 0; c_ < 8; ++c_)                                            \
        xr[c_] = *(const floatx4*)(xp_ + (c_ >> 1) * 32 + (c_ & 1) * 4);        \
    }                                                                           \
    {                                                                           \
      const unsigned short* sb_ = ((S) & 1) ? sW1 : sW0;                        \
      _Pragma("unroll")                                                         \
      for (int ks = 0; ks < 4; ++ks) {                                          \
        _Pragma("unroll")                                                       \
        for (int nf = 0; nf < 8; ++nf) {                                        \
          short8 bf_ = *(const short8*)                                         \
              &sb_[(nf * 16 + l15) * 128 + (((ks * 4 + quad) ^ l15) << 3)];     \
          acc[nf] = __builtin_amdgcn_mfma_f32_16x16x32_bf16(                    \
              xf[(J) % 3][ks], bf_, acc[nf], 0, 0, 0);                          \
        }                                                                       \
      }                                                                         \
    }                                                                           \
    if ((J) == (I)) {                                                           \
      float* oi_ = out + (size_t)(I) * XSTRIDE                                  \
                       + (size_t)(m0 + wave * 16 + quad * 4) * DD;              \
      _Pragma("unroll")                                                         \
      for (int nf = 0; nf < 8; ++nf) {                                          \
        const int ng_ = nf * 16 + l15;                                          \
        const float bs_ = sbias[(I) * DD + ng_];                                \
        _Pragma("unroll")                                                       \
        for (int r_ = 0; r_ < 4; ++r_)                                          \
          oi_[(size_t)r_ * DD + ng_] = acc[nf][r_] + bs_;                       \
        acc[nf] = (floatx4){0.f, 0.f, 0.f, 0.f};                                \
      }                                                                         \
    }                                                                           \
    if (HASNEXT) {                                                              \
      unsigned short* sd_ = (((S) + 1) & 1) ? sW1 : sW0;                        \
      _Pragma("unroll")                                                         \
      for (int u_ = 0; u_ < 8; ++u_) {                                          \
        const int ul_ = whalf * 8 + u_;                                         \
        *(short8*)&sd_[wrow * 128 + ((ul_ ^ (wrow & 15)) << 3)] =               \
            pack8(wreg[2 * u_], wreg[2 * u_ + 1]);                              \
      }                                                                         \
      __builtin_amdgcn_sched_barrier(0);                                        \
      asm volatile("s_waitcnt lgkmcnt(0)" ::: "memory");                        \
      __builtin_amdgcn_sched_barrier(0);                                        \
      __builtin_amdgcn_s_barrier();                                             \
      __builtin_amdgcn_sched_barrier(0);                                        \
    }                                                                           \
  }

__global__ __launch_bounds__(256, 2)
void seq2d_kernel(const float* __restrict__ X,
                  const float* __restrict__ W,
                  const float* __restrict__ Bv,
                  float* __restrict__ out) {
    const int m0 = blockIdx.x * BM;

    __shared__ unsigned short sW0[DD * 128];   // 32 KB, XOR-swizzled
    __shared__ unsigned short sW1[DD * 128];   // 32 KB
    __shared__ float sbias[NOUT * DD];         // 4 KB: summed bias per (i, col)

    const int tid  = threadIdx.x;
    const int lane = tid & 63;
    const int wave = tid >> 6;          // 0..3, each owns 16 batch rows
    const int l15  = lane & 15;
    const int quad = lane >> 4;

    // Per-lane X fragment base: row = m0 + wave*16 + (lane&15), k-off quad*8.
    const float* xb = X + (size_t)(m0 + wave * 16 + l15) * DD + quad * 8;

    // W staging geometry: thread t -> row t&127, float-cols (t>>7)*64 .. +63.
    const int wrow  = tid & 127;
    const int whalf = tid >> 7;

    // Register state (all statically indexed):
    floatx4 xr[8];        // raw f32 of one in-flight X tile (32 VGPR)
    short8  xf[3][4];     // bf16 A-frag window, 3 tiles (48 VGPR)
    floatx4 wreg[16];     // in-flight W tile (64 VGPR)
    floatx4 acc[8];       // accumulator, 16 rows x 128 cols (32 VGPR)

    // ---- prologue ----
    // X[0] raw issue (oldest in the queue):
#pragma unroll
    for (int c = 0; c < 8; ++c)
        xr[c] = *(const floatx4*)(xb + (c >> 1) * 32 + (c & 1) * 4);

    // bias sums (tiny, one-time):
    if (tid < DD) {
#pragma unroll
        for (int i = 0; i < NOUT; ++i) {
            const int jlo = (i - BAND > 0) ? (i - BAND) : 0;
            float s = 0.f;
            for (int j = jlo; j <= i; ++j)
                s += Bv[(i * NIN + j) * DD + tid];
            sbias[i * DD + tid] = s;
        }
    }

    // W[0,0] -> buf0:
    {
        const float* ws = W + (size_t)wrow * DD + whalf * 64;
#pragma unroll
        for (int w = 0; w < 16; ++w)
            wreg[w] = *(const floatx4*)(ws + w * 4);
#pragma unroll
        for (int u = 0; u < 8; ++u) {
            const int ul = whalf * 8 + u;
            *(short8*)&sW0[wrow * 128 + ((ul ^ (wrow & 15)) << 3)] =
                pack8(wreg[2 * u], wreg[2 * u + 1]);
        }
    }
#pragma unroll
    for (int n = 0; n < 8; ++n)
        acc[n] = (floatx4){0.f, 0.f, 0.f, 0.f};

    __syncthreads();   // one-time full drain (X[0] already landed in xr).

    // ---- 21 statically-unrolled (i,j) steps ----
    STEP( 0, 0, 0, 1, 1, 1, 0, 1)
    STEP( 1, 1, 0, 1, 1, 1, 1, 0)
    STEP( 2, 1, 1, 0, 1, 2, 0, 1)
    STEP( 3, 2, 0, 1, 1, 2, 1, 0)
    STEP( 4, 2, 1, 0, 1, 2, 2, 0)
    STEP( 5, 2, 2, 0, 1, 3, 1, 1)
    STEP( 6, 3, 1, 1, 1, 3, 2, 0)
    STEP( 7, 3, 2, 0, 1, 3, 3, 0)
    STEP( 8, 3, 3, 0, 1, 4, 2, 1)
    STEP( 9, 4, 2, 1, 1, 4, 3, 0)
    STEP(10, 4, 3, 0, 1, 4, 4, 0)
    STEP(11, 4, 4, 0, 1, 5, 3, 1)
    STEP(12, 5, 3, 1, 1, 5, 4, 0)
    STEP(13, 5, 4, 0, 1, 5, 5, 0)
    STEP(14, 5, 5, 0, 1, 6, 4, 1)
    STEP(15, 6, 4, 1, 1, 6, 5, 0)
    STEP(16, 6, 5, 0, 1, 6, 6, 0)
    STEP(17, 6, 6, 0, 1, 7, 5, 1)
    STEP(18, 7, 5, 1, 1, 7, 6, 0)
    STEP(19, 7, 6, 0, 1, 7, 7, 0)
    STEP(20, 7, 7, 0, 0, 0, 0, 0)
}

extern "C" void kernel_launch(void* const* d_in, const int* in_sizes, int n_in,
                              void* d_out, int out_size, void* d_ws, size_t ws_size,
                              hipStream_t stream) {
    const float* X  = (const float*)d_in[0];
    const float* W  = (const float*)d_in[1];
    const float* Bv = (const float*)d_in[2];
    float* out = (float*)d_out;

    dim3 grid(BATCH / BM);
    seq2d_kernel<<<grid, 256, 0, stream>>>(X, W, Bv, out);
}